// Round 2
// 347.492 us; speedup vs baseline: 1.0082x; 1.0082x over previous
//
#include <hip/hip_runtime.h>
#include <math.h>

#define BSZ 128
#define KTOT 196608            // 3*256*256
#define NBLK1 256              // split-K blocks (1 per CU)
#define KC (KTOT / NBLK1)      // 768
#define BK 128                 // k per superslab (512 B per row -> contiguous half-wave reads)
#define NSLAB (KC / BK)        // 6
#define RS 136                 // LDS row stride in bf16 (128 + 8 pad; 272B rows, 16B-aligned)
#define REGF 0.01f
#define NITER 8                // contraction ~0.02/iter; converged ~1e-13 by iter 8

typedef short bf16x8 __attribute__((ext_vector_type(8)));
typedef float f32x4 __attribute__((ext_vector_type(4)));

__device__ __forceinline__ unsigned short f2bf(float f) {
    union { float f; unsigned int u; } x; x.f = f;
    unsigned int r = x.u + 0x7fffu + ((x.u >> 16) & 1u);   // RNE
    return (unsigned short)(r >> 16);
}

// Split-K bf16-MFMA GEMM, contiguity-first staging, conservative sync:
// block b owns a 768-float K-chunk of all 128 rows of each array. 6 superslabs
// of BK=128 floats; each wave-level global load reads 2 rows x 512 B CONTIGUOUS
// (lane>>5 = row pair half, lane&31 = float4 slot), replacing the old 128-B
// DRAM scatter. 8 waves/block (16 output rows each). Plain __syncthreads only.
__global__ __launch_bounds__(512, 2) void dot_kernel(
    const float* __restrict__ imgs, const float* __restrict__ imgs_w,
    const float* __restrict__ target, float* __restrict__ P,
    float* __restrict__ x2P, float* __restrict__ y2P)
{
    __shared__ unsigned short Abf[BSZ * RS];   // delta, [row][k] k-contiguous
    __shared__ unsigned short Bbf[BSZ * RS];   // target
    __shared__ float x2s[BSZ], y2s[BSZ];
    const int t = threadIdx.x;
    const int bid = blockIdx.x;
    const long kbase = (long)bid * KC;

    const int lane = t & 63;
    const int wv = t >> 6;        // 8 waves
    const int fr = lane & 15;     // fragment row/col within 16-tile
    const int fq = lane >> 4;     // quad
    const int wrow0 = wv * 16;    // this wave's output-row block (and staging rows)

    // staging coords: half-wave owns one row; lane&31 indexes the float4 slot
    const int c = lane & 31;
    const int rhalf = lane >> 5;  // 0/1

    // per-thread global base: row wrow0+rhalf, k = kbase + c*4
    const long base0 = (long)(wrow0 + rhalf) * KTOT + kbase + c * 4;
    const float* pw = imgs_w + base0;
    const float* pi = imgs + base0;
    const float* pt = target + base0;

    f32x4 acc[8];
#pragma unroll
    for (int ct = 0; ct < 8; ++ct) acc[ct] = (f32x4){0.f, 0.f, 0.f, 0.f};

    // group g (0..7 per slab): rows wrow0 + 2g + rhalf; one float4 per array
#define ISSUE(set, s, g) do {                                                  \
    const long off_ = (long)(2 * (g)) * KTOT + (long)(s) * BK;                 \
    set##w = *(const float4*)(pw + off_);                                      \
    set##i = *(const float4*)(pi + off_);                                      \
    set##t = *(const float4*)(pt + off_);                                      \
} while (0)

#define PROC(set, g) do {                                                      \
    const int row_ = wrow0 + 2 * (g) + rhalf;                                  \
    const float4 w4 = set##w, i4 = set##i, t4 = set##t;                        \
    const float d0 = w4.x - i4.x, d1 = w4.y - i4.y;                            \
    const float d2 = w4.z - i4.z, d3 = w4.w - i4.w;                            \
    float sx = d0 * d0 + d1 * d1 + d2 * d2 + d3 * d3;                          \
    float sy = t4.x * t4.x + t4.y * t4.y + t4.z * t4.z + t4.w * t4.w;          \
    sx += __shfl_xor(sx, 1);  sy += __shfl_xor(sy, 1);                         \
    sx += __shfl_xor(sx, 2);  sy += __shfl_xor(sy, 2);                         \
    sx += __shfl_xor(sx, 4);  sy += __shfl_xor(sy, 4);                         \
    sx += __shfl_xor(sx, 8);  sy += __shfl_xor(sy, 8);                         \
    sx += __shfl_xor(sx, 16); sy += __shfl_xor(sy, 16);                        \
    if ((lane & 31) == 0) { x2s[row_] += sx; y2s[row_] += sy; }                \
    ushort4 pa, pb;                                                            \
    pa.x = f2bf(d0);   pa.y = f2bf(d1);   pa.z = f2bf(d2);   pa.w = f2bf(d3);  \
    pb.x = f2bf(t4.x); pb.y = f2bf(t4.y); pb.z = f2bf(t4.z); pb.w = f2bf(t4.w);\
    *(ushort4*)&Abf[row_ * RS + c * 4] = pa;                                   \
    *(ushort4*)&Bbf[row_ * RS + c * 4] = pb;                                   \
} while (0)

    float4 Aw, Ai, At;
    float4 Bw, Bi, Bt;

    // prologue: two groups in flight; zero norm accumulators
    ISSUE(A, 0, 0);
    ISSUE(B, 0, 1);
    if (t < BSZ) { x2s[t] = 0.f; y2s[t] = 0.f; }
    __syncthreads();

    for (int s = 0; s < NSLAB; ++s) {
        // stage slab s (depth-2 register pipeline; tail prefetches next slab)
#pragma unroll
        for (int g = 0; g < 8; g += 2) {
            PROC(A, g);
            if (g + 2 < 8) ISSUE(A, s, g + 2);
            else if (s + 1 < NSLAB) ISSUE(A, s + 1, 0);
            PROC(B, g + 1);
            if (g + 3 < 8) ISSUE(B, s, g + 3);
            else if (s + 1 < NSLAB) ISSUE(B, s + 1, 1);
        }
        __syncthreads();   // slab staged (full drain; next-slab prefetch lands too)
        // one K=128 MFMA phase: 4 sub-K steps x 8 col-tiles
#pragma unroll
        for (int ks = 0; ks < 4; ++ks) {
            const bf16x8 a0 = *(const bf16x8*)&Abf[(wrow0 + fr) * RS + ks * 32 + fq * 8];
#pragma unroll
            for (int ct = 0; ct < 8; ++ct) {
                const bf16x8 b = *(const bf16x8*)&Bbf[(ct * 16 + fr) * RS + ks * 32 + fq * 8];
                acc[ct] = __builtin_amdgcn_mfma_f32_16x16x32_bf16(a0, b, acc[ct], 0, 0, 0);
            }
        }
        __syncthreads();   // readers done before next slab overwrites LDS
    }
#undef ISSUE
#undef PROC

    // norms -> per-block global arrays (x2s/y2s hold block partials)
    if (t < BSZ) {
        x2P[bid * BSZ + t] = x2s[t];
        y2P[bid * BSZ + t] = y2s[t];
    }

    // store partial tile: C/D layout col=lane&15, row=quad*4+reg (m89/m91)
    float* Pb = P + ((size_t)bid << 14);
#pragma unroll
    for (int ct = 0; ct < 8; ++ct)
#pragma unroll
        for (int r = 0; r < 4; ++r)
            Pb[(wrow0 + fq * 4 + r) * BSZ + ct * 16 + fr] = acc[ct][r];
}

// Sum 256 partials (ILP-16), finish norms, build C = sqrt(relu(x2_i + y2_j - 2S)).
__global__ __launch_bounds__(256) void reduce_kernel(
    const float* __restrict__ P, const float* __restrict__ x2P,
    const float* __restrict__ y2P, float* __restrict__ C)
{
    __shared__ float y2loc[BSZ];
    __shared__ float x2loc[2];
    const int t = threadIdx.x;
    const int b = blockIdx.x;          // 64 blocks; rows {2b, 2b+1}
    if (t < 2) x2loc[t] = 0.f;
    __syncthreads();
    if (t < BSZ) {
        float s = 0.f;
#pragma unroll 8
        for (int bb = 0; bb < NBLK1; ++bb) s += y2P[bb * BSZ + t];
        y2loc[t] = s;
    } else {
        const int t2 = t - BSZ;
        const int rsel = t2 >> 6;       // 0/1
        const int part = t2 & 63;       // 64 threads x 4 blocks each
        const int row = 2 * b + rsel;
        float s = 0.f;
#pragma unroll
        for (int m = 0; m < 4; ++m) s += x2P[(part * 4 + m) * BSZ + row];
        atomicAdd(&x2loc[rsel], s);
    }
    __syncthreads();
    const int o = b * 256 + t;
    const int i = o >> 7, j = o & 127;
    float a[16];
#pragma unroll
    for (int m = 0; m < 16; ++m) a[m] = 0.f;
    for (int k0 = 0; k0 < NBLK1; k0 += 16) {
#pragma unroll
        for (int m = 0; m < 16; ++m) a[m] += P[(size_t)(k0 + m) * 16384 + o];
    }
    float s = 0.f;
#pragma unroll
    for (int m = 0; m < 16; ++m) s += a[m];
    C[o] = sqrtf(fmaxf(x2loc[i - 2 * b] + y2loc[j] - 2.f * s, 0.f));
}

// Single-block sinkhorn on prebuilt C; exp-factorized (two 128x128 matvecs/iter).
__global__ __launch_bounds__(1024) void sinkhorn_kernel(
    const float* __restrict__ Cg, float* __restrict__ out)
{
    __shared__ float C_lds[BSZ * BSZ];
    __shared__ float w_s[BSZ];           // exp(-v)
    __shared__ float g_s[BSZ];           // exp(-u)
    __shared__ float u_s[BSZ], v_s[BSZ];
    const int t = threadIdx.x;
    const int lane = t & 63;
    const int wave = t >> 6;
    const int rgrp = wave * 8 + (lane >> 3);
    const int off16 = (lane & 7) * 16;

#pragma unroll
    for (int q = 0; q < 4; ++q)
        *(float4*)&C_lds[q * 4096 + t * 4] = *(const float4*)&Cg[q * 4096 + t * 4];
    if (t < BSZ) w_s[t] = 1.f;
    __syncthreads();

    float rowE[16], colF[16], mrow, mcol;
    {
        float tmp[16]; float m = -1e30f;
#pragma unroll
        for (int k = 0; k < 16; ++k) { tmp[k] = C_lds[rgrp * BSZ + off16 + k]; m = fmaxf(m, tmp[k]); }
        m = fmaxf(m, __shfl_xor(m, 1)); m = fmaxf(m, __shfl_xor(m, 2)); m = fmaxf(m, __shfl_xor(m, 4));
        mrow = m;
#pragma unroll
        for (int k = 0; k < 16; ++k) rowE[k] = __expf(tmp[k] - mrow);
    }
    {
        float tmp[16]; float m = -1e30f;
#pragma unroll
        for (int k = 0; k < 16; ++k) { tmp[k] = C_lds[(off16 + k) * BSZ + rgrp]; m = fmaxf(m, tmp[k]); }
        m = fmaxf(m, __shfl_xor(m, 1)); m = fmaxf(m, __shfl_xor(m, 2)); m = fmaxf(m, __shfl_xor(m, 4));
        mcol = m;
#pragma unroll
        for (int k = 0; k < 16; ++k) colF[k] = __expf(tmp[k] - mcol);
    }

    const float log_ab = -logf(128.f);
    float u_cur = 0.f, v_cur = 0.f;

    for (int it = 0; it < NITER; ++it) {
        float acc = 0.f;
#pragma unroll
        for (int k = 0; k < 16; ++k) acc += rowE[k] * w_s[off16 + k];
        acc += __shfl_xor(acc, 1); acc += __shfl_xor(acc, 2); acc += __shfl_xor(acc, 4);
        const float lse = mrow + __logf(acc);
        u_cur = REGF * (log_ab - lse + u_cur);
        if ((lane & 7) == 0) g_s[rgrp] = __expf(-u_cur);
        __syncthreads();
        float acc2 = 0.f;
#pragma unroll
        for (int k = 0; k < 16; ++k) acc2 += colF[k] * g_s[off16 + k];
        acc2 += __shfl_xor(acc2, 1); acc2 += __shfl_xor(acc2, 2); acc2 += __shfl_xor(acc2, 4);
        const float lse2 = mcol + __logf(acc2);
        v_cur = REGF * (log_ab - lse2 + v_cur);
        if ((lane & 7) == 0) w_s[rgrp] = __expf(-v_cur);
        __syncthreads();
    }

    if ((lane & 7) == 0) { u_s[rgrp] = u_cur; v_s[rgrp] = v_cur; }
    __syncthreads();
    if (t == 0) {
        float su = 0.f;
        for (int i = 0; i < BSZ; ++i) su += u_s[i] + v_s[i];
        out[0] = su / 128.f;
    }
}

extern "C" void kernel_launch(void* const* d_in, const int* in_sizes, int n_in,
                              void* d_out, int out_size, void* d_ws, size_t ws_size,
                              hipStream_t stream) {
    const float* imgs   = (const float*)d_in[0];
    const float* imgs_w = (const float*)d_in[1];
    const float* target = (const float*)d_in[2];
    float* out = (float*)d_out;
    float* wsf = (float*)d_ws;

    float* P   = wsf;                                  // 256 * 16384 partials
    float* x2P = wsf + (size_t)NBLK1 * BSZ * BSZ;      // 256 * 128
    float* y2P = x2P + NBLK1 * BSZ;                    // 256 * 128
    float* C   = y2P + NBLK1 * BSZ;                    // 128 * 128

    dot_kernel<<<NBLK1, 512, 0, stream>>>(imgs, imgs_w, target, P, x2P, y2P);
    reduce_kernel<<<BSZ * BSZ / 256, 256, 0, stream>>>(P, x2P, y2P, C);
    sinkhorn_kernel<<<1, 1024, 0, stream>>>(C, out);
}